// Round 2
// baseline (211.106 us; speedup 1.0000x reference)
//
#include <hip/hip_runtime.h>
#include <hip/hip_bf16.h>

// Problem: B=4, L=2048, D_MODEL=1024, H=16, D_QKV=64.
// KEY INSIGHT: reference einsum 'bhlk,blhd->blhd' contracts k over logits ONLY;
// softmax(axis=3) sums to 1, so attention output == v. Entire net reduces to
//   out = x @ Wc + fc_b,  Wc[m][j] = sum_{hd} w_v[h][m][d] * fc_w[j][hd]
// q/k/mask/softmax are dead. Two bf16 MFMA GEMMs: Wc fold (1024^3) + main (8192x1024x1024).

typedef __attribute__((ext_vector_type(8))) short bf16x8;
typedef __attribute__((ext_vector_type(4))) float f32x4;

__device__ __forceinline__ f32x4 mfma16(bf16x8 a, bf16x8 b, f32x4 c) {
  return __builtin_amdgcn_mfma_f32_16x16x32_bf16(a, b, c, 0, 0, 0);
}

// fp32 -> bf16 bits, round-to-nearest-even
__device__ __forceinline__ unsigned short f2b(float f) {
  unsigned int u = __builtin_bit_cast(unsigned int, f);
  return (unsigned short)((u + 0x7fffu + ((u >> 16) & 1u)) >> 16);
}

__global__ void cast_f32_bf16(const float* __restrict__ in,
                              unsigned short* __restrict__ out, int n) {
  int i = blockIdx.x * 256 + threadIdx.x;
  if (i < n) out[i] = f2b(in[i]);
}

// wvp[m][h*64+d] = w_v[h][m][d]   (1024 x 1024, row m, col hd; k-contiguous rows)
__global__ void pack_wv(const float* __restrict__ wv, unsigned short* __restrict__ wvp) {
  int tid = blockIdx.x * 256 + threadIdx.x;   // 0 .. 1048575
  int hd = tid & 1023, m = tid >> 10;
  int h = hd >> 6, d = hd & 63;
  wvp[m * 1024 + hd] = f2b(wv[(h << 16) + (m << 6) + d]);
}

// C(128x128 per block) = A(rows x 1024 bf16) * Bt(rows x 1024 bf16)^T, K=1024.
// 4 waves (2x2), each wave 64x64 (16 MFMA subtiles). Direct per-lane 16B fragment loads.
// Verified pattern (learn_hip m92): A-frag row=lane&15, k=quad*8+j; B-frag identical from Bt rows.
__device__ __forceinline__ void gemm_core(const unsigned short* __restrict__ A,
                                          const unsigned short* __restrict__ Bt,
                                          int row0, int col0, f32x4 acc[16]) {
  int lane = threadIdx.x & 63, l16 = lane & 15, quad = lane >> 4;
  const unsigned short* Ab = A + (row0 + l16) * 1024 + quad * 8;
  const unsigned short* Bb = Bt + (col0 + l16) * 1024 + quad * 8;
  for (int k0 = 0; k0 < 1024; k0 += 32) {
    bf16x8 af[4], bfr[4];
#pragma unroll
    for (int t = 0; t < 4; t++) {
      af[t]  = *reinterpret_cast<const bf16x8*>(Ab + t * 16 * 1024 + k0);
      bfr[t] = *reinterpret_cast<const bf16x8*>(Bb + t * 16 * 1024 + k0);
    }
#pragma unroll
    for (int rt = 0; rt < 4; rt++)
#pragma unroll
      for (int ct = 0; ct < 4; ct++)
        acc[rt * 4 + ct] = mfma16(af[rt], bfr[ct], acc[rt * 4 + ct]);
  }
}

// wcT[j][m] = sum_k fc_w[j][k] * wvp[m][k]  == Wc[m][j].  1024x1024, bf16 out.
__global__ __launch_bounds__(256) void wc_gemm(const unsigned short* __restrict__ fcwb,
                                               const unsigned short* __restrict__ wvp,
                                               unsigned short* __restrict__ wcT) {
  int wid = threadIdx.x >> 6;
  int lane = threadIdx.x & 63, l16 = lane & 15, quad = lane >> 4;
  int row0 = blockIdx.y * 128 + (wid >> 1) * 64;   // j
  int col0 = blockIdx.x * 128 + (wid & 1) * 64;    // m
  f32x4 acc[16];
#pragma unroll
  for (int t = 0; t < 16; t++) acc[t] = (f32x4){0.f, 0.f, 0.f, 0.f};
  gemm_core(fcwb, wvp, row0, col0, acc);
#pragma unroll
  for (int rt = 0; rt < 4; rt++)
#pragma unroll
    for (int ct = 0; ct < 4; ct++) {
      int j = row0 + rt * 16 + quad * 4;          // C row (+r)
      int m = col0 + ct * 16 + l16;               // C col
      f32x4 a = acc[rt * 4 + ct];
#pragma unroll
      for (int r = 0; r < 4; r++)
        wcT[(j + r) * 1024 + m] = f2b(a[r]);
    }
}

// out[i][j] = sum_m xb[i][m] * wcT[j][m] + fcb[j].  M=8192, N=1024, K=1024, fp32 out.
__global__ __launch_bounds__(256) void final_gemm(const unsigned short* __restrict__ xb,
                                                  const unsigned short* __restrict__ wcT,
                                                  const float* __restrict__ fcb,
                                                  float* __restrict__ out) {
  int wid = threadIdx.x >> 6;
  int lane = threadIdx.x & 63, l16 = lane & 15, quad = lane >> 4;
  int row0 = blockIdx.y * 128 + (wid >> 1) * 64;
  int col0 = blockIdx.x * 128 + (wid & 1) * 64;
  f32x4 acc[16];
#pragma unroll
  for (int t = 0; t < 16; t++) acc[t] = (f32x4){0.f, 0.f, 0.f, 0.f};
  gemm_core(xb, wcT, row0, col0, acc);
#pragma unroll
  for (int ct = 0; ct < 4; ct++) {
    int j = col0 + ct * 16 + l16;
    float bias = fcb[j];
#pragma unroll
    for (int rt = 0; rt < 4; rt++) {
      int i0 = row0 + rt * 16 + quad * 4;
      f32x4 a = acc[rt * 4 + ct];
#pragma unroll
      for (int r = 0; r < 4; r++) out[(i0 + r) * 1024 + j] = a[r] + bias;
    }
  }
}

extern "C" void kernel_launch(void* const* d_in, const int* in_sizes, int n_in,
                              void* d_out, int out_size, void* d_ws, size_t ws_size,
                              hipStream_t stream) {
  const float* x   = (const float*)d_in[0];
  // d_in[1] mask, d_in[2] w_q, d_in[3] w_k: dead per reference semantics
  const float* wv  = (const float*)d_in[4];
  const float* fcw = (const float*)d_in[5];
  const float* fcb = (const float*)d_in[6];
  float* out = (float*)d_out;

  // workspace layout (22 MB total)
  char* ws = (char*)d_ws;
  unsigned short* xb   = (unsigned short*)(ws);              // 16 MB (8192x1024 bf16)
  unsigned short* wvp  = (unsigned short*)(ws + 16777216);   // 2 MB  (1024x1024 bf16)
  unsigned short* fcwb = (unsigned short*)(ws + 18874368);   // 2 MB  (1024x1024 bf16)
  unsigned short* wcT  = (unsigned short*)(ws + 20971520);   // 2 MB  (1024x1024 bf16)

  cast_f32_bf16<<<32768, 256, 0, stream>>>(x, xb, 8388608);
  cast_f32_bf16<<<4096, 256, 0, stream>>>(fcw, fcwb, 1048576);
  pack_wv<<<4096, 256, 0, stream>>>(wv, wvp);
  wc_gemm<<<dim3(8, 8), 256, 0, stream>>>(fcwb, wvp, wcT);
  final_gemm<<<dim3(8, 64), 256, 0, stream>>>(xb, wcT, fcb, out);
}

// Round 3
// 153.508 us; speedup vs baseline: 1.3752x; 1.3752x over previous
//
#include <hip/hip_runtime.h>
#include <hip/hip_bf16.h>

// Problem: B=4, L=2048, D_MODEL=1024, H=16, D_QKV=64.
// Reference einsum 'bhlk,blhd->blhd' contracts k over logits only; softmax sums to 1,
// so attention output == v and the net reduces to:
//   out = x @ Wc + fc_b,  Wc[m][j] = sum_{hd} w_v[h][m][d] * fc_w[j][hd]
// Pipeline: cast4 (x->bf16) ; fold_w (Wc^T bf16, fused cast+pack+gemm) ; final_gemm (m97-style).

typedef __attribute__((ext_vector_type(8))) short bf16x8;
typedef __attribute__((ext_vector_type(4))) float f32x4;
typedef __attribute__((ext_vector_type(4))) unsigned short u16x4;

__device__ __forceinline__ f32x4 mfma16(bf16x8 a, bf16x8 b, f32x4 c) {
  return __builtin_amdgcn_mfma_f32_16x16x32_bf16(a, b, c, 0, 0, 0);
}

// fp32 -> bf16 bits, round-to-nearest-even
__device__ __forceinline__ unsigned short f2b(float f) {
  unsigned int u = __builtin_bit_cast(unsigned int, f);
  return (unsigned short)((u + 0x7fffu + ((u >> 16) & 1u)) >> 16);
}

__device__ __forceinline__ bf16x8 cvt8(float4 a, float4 b) {
  bf16x8 r;
  r[0] = (short)f2b(a.x); r[1] = (short)f2b(a.y); r[2] = (short)f2b(a.z); r[3] = (short)f2b(a.w);
  r[4] = (short)f2b(b.x); r[5] = (short)f2b(b.y); r[6] = (short)f2b(b.z); r[7] = (short)f2b(b.w);
  return r;
}

// async global->LDS, 16 B per lane (m97 pattern)
__device__ __forceinline__ void gld_lds16(const void* g, void* l) {
  __builtin_amdgcn_global_load_lds((const __attribute__((address_space(1))) unsigned int*)g,
                                   (__attribute__((address_space(3))) unsigned int*)l, 16, 0, 0);
}

// x fp32 -> bf16, 4 elems/thread
__global__ void cast4(const float* __restrict__ in, unsigned short* __restrict__ out) {
  int i = (blockIdx.x * 256 + threadIdx.x) * 4;
  float4 v = *reinterpret_cast<const float4*>(in + i);
  u16x4 o;
  o[0] = f2b(v.x); o[1] = f2b(v.y); o[2] = f2b(v.z); o[3] = f2b(v.w);
  *reinterpret_cast<u16x4*>(out + i) = o;
}

// wcT[j][m] = sum_{hd} fc_w[j][hd] * w_v[hd>>6][m][hd&63]   (1024x1024 bf16 out)
// 64x64 block tile, 4 waves 2x2 (32x32 each), fp32 inputs converted in-register.
__global__ __launch_bounds__(256) void fold_w(const float* __restrict__ fcw,
                                              const float* __restrict__ wv,
                                              unsigned short* __restrict__ wcT) {
  int wid = threadIdx.x >> 6, lane = threadIdx.x & 63, l16 = lane & 15, quad = lane >> 4;
  int wr = wid >> 1, wc = wid & 1;
  int row0 = blockIdx.y * 64 + wr * 32;   // j
  int col0 = blockIdx.x * 64 + wc * 32;   // m
  f32x4 acc[2][2];
#pragma unroll
  for (int a = 0; a < 2; a++)
#pragma unroll
    for (int b = 0; b < 2; b++) acc[a][b] = (f32x4){0.f, 0.f, 0.f, 0.f};

  for (int k0 = 0; k0 < 1024; k0 += 32) {
    int kk = k0 + quad * 8;
    int h = kk >> 6, d = kk & 63;
    bf16x8 af[2], bfr[2];
#pragma unroll
    for (int rt = 0; rt < 2; rt++) {
      const float* pa = fcw + (row0 + rt * 16 + l16) * 1024 + kk;
      af[rt] = cvt8(*reinterpret_cast<const float4*>(pa), *reinterpret_cast<const float4*>(pa + 4));
    }
#pragma unroll
    for (int ct = 0; ct < 2; ct++) {
      const float* pb = wv + h * 65536 + (col0 + ct * 16 + l16) * 64 + d;
      bfr[ct] = cvt8(*reinterpret_cast<const float4*>(pb), *reinterpret_cast<const float4*>(pb + 4));
    }
#pragma unroll
    for (int rt = 0; rt < 2; rt++)
#pragma unroll
      for (int ct = 0; ct < 2; ct++) acc[rt][ct] = mfma16(af[rt], bfr[ct], acc[rt][ct]);
  }
#pragma unroll
  for (int rt = 0; rt < 2; rt++)
#pragma unroll
    for (int ct = 0; ct < 2; ct++) {
      int j0 = row0 + rt * 16 + quad * 4;
      int m = col0 + ct * 16 + l16;
#pragma unroll
      for (int r = 0; r < 4; r++) wcT[(j0 + r) * 1024 + m] = f2b(acc[rt][ct][r]);
    }
}

// out[i][j] = sum_m xb[i][m]*wcT[j][m] + fcb[j].  M=8192,N=1024,K=1024.
// m97 structure: 128x128 block tile, BK=32, global_load_lds(16B) staging, ds_read_b128 frags.
// grid (M-fastest, 64x8): consecutive blocks share the 2MB B matrix -> L2-resident, A fetched once.
__global__ __launch_bounds__(256) void final_gemm(const unsigned short* __restrict__ xb,
                                                  const unsigned short* __restrict__ wcT,
                                                  const float* __restrict__ fcb,
                                                  float* __restrict__ out) {
  __shared__ __align__(16) unsigned short As[128 * 32];
  __shared__ __align__(16) unsigned short Bs[128 * 32];
  int t = threadIdx.x, wid = t >> 6, lane = t & 63, l16 = lane & 15, quad = lane >> 4;
  int wr = wid >> 1, wc = wid & 1;
  int row0 = blockIdx.x * 128;   // M tile
  int col0 = blockIdx.y * 128;   // N tile

  // staging: chunk c covers LDS bytes [c*16, c*16+16) = tile row c>>2, k-quad c&3.
  int sr = t >> 2, skq = t & 3;  // i=0 chunk; i=1 chunk is row sr+64, same kq
  const unsigned short* Ag0 = xb + (row0 + sr) * 1024 + skq * 8;
  const unsigned short* Bg0 = wcT + (col0 + sr) * 1024 + skq * 8;

  f32x4 acc[16];
#pragma unroll
  for (int i = 0; i < 16; i++) acc[i] = (f32x4){0.f, 0.f, 0.f, 0.f};

  for (int k0 = 0; k0 < 1024; k0 += 32) {
    __syncthreads();
    gld_lds16(Ag0 + k0, &As[t * 8]);
    gld_lds16(Ag0 + 64 * 1024 + k0, &As[(256 + t) * 8]);
    gld_lds16(Bg0 + k0, &Bs[t * 8]);
    gld_lds16(Bg0 + 64 * 1024 + k0, &Bs[(256 + t) * 8]);
    __syncthreads();

    bf16x8 af[4], bfr[4];
#pragma unroll
    for (int rt = 0; rt < 4; rt++)
      af[rt] = *reinterpret_cast<const bf16x8*>(&As[(wr * 64 + rt * 16 + l16) * 32 + quad * 8]);
#pragma unroll
    for (int ct = 0; ct < 4; ct++)
      bfr[ct] = *reinterpret_cast<const bf16x8*>(&Bs[(wc * 64 + ct * 16 + l16) * 32 + quad * 8]);
#pragma unroll
    for (int rt = 0; rt < 4; rt++)
#pragma unroll
      for (int ct = 0; ct < 4; ct++)
        acc[rt * 4 + ct] = mfma16(af[rt], bfr[ct], acc[rt * 4 + ct]);
  }

#pragma unroll
  for (int ct = 0; ct < 4; ct++) {
    int j = col0 + wc * 64 + ct * 16 + l16;
    float bias = fcb[j];
#pragma unroll
    for (int rt = 0; rt < 4; rt++) {
      int i0 = row0 + wr * 64 + rt * 16 + quad * 4;
      f32x4 a = acc[rt * 4 + ct];
#pragma unroll
      for (int r = 0; r < 4; r++) out[(i0 + r) * 1024 + j] = a[r] + bias;
    }
  }
}

extern "C" void kernel_launch(void* const* d_in, const int* in_sizes, int n_in,
                              void* d_out, int out_size, void* d_ws, size_t ws_size,
                              hipStream_t stream) {
  const float* x   = (const float*)d_in[0];
  // d_in[1] mask, d_in[2] w_q, d_in[3] w_k: dead per reference semantics
  const float* wv  = (const float*)d_in[4];
  const float* fcw = (const float*)d_in[5];
  const float* fcb = (const float*)d_in[6];
  float* out = (float*)d_out;

  char* ws = (char*)d_ws;
  unsigned short* xb  = (unsigned short*)(ws);              // 16 MB (8192x1024 bf16)
  unsigned short* wcT = (unsigned short*)(ws + 16777216);   // 2 MB  (1024x1024 bf16)

  cast4<<<8192, 256, 0, stream>>>(x, xb);
  fold_w<<<dim3(16, 16), 256, 0, stream>>>(fcw, wv, wcT);
  final_gemm<<<dim3(64, 8), 256, 0, stream>>>(xb, wcT, fcb, out);
}

// Round 4
// 151.057 us; speedup vs baseline: 1.3975x; 1.0162x over previous
//
#include <hip/hip_runtime.h>
#include <hip/hip_bf16.h>

// Problem: B=4, L=2048, D_MODEL=1024, H=16, D_QKV=64.
// Reference einsum 'bhlk,blhd->blhd' contracts k over logits only; softmax sums to 1,
// so attention output == v and the net reduces to:
//   out = x @ Wc + fc_b,  Wc[m][j] = sum_{hd} w_v[h][m][d] * fc_w[j][hd]
// Pipeline: cast8 (x->bf16) ; fold_w (Wc^T bf16, split-K 512-thread) ; final_gemm (BK=64 dual-slab m97).

typedef __attribute__((ext_vector_type(8))) short bf16x8;
typedef __attribute__((ext_vector_type(4))) float f32x4;

__device__ __forceinline__ f32x4 mfma16(bf16x8 a, bf16x8 b, f32x4 c) {
  return __builtin_amdgcn_mfma_f32_16x16x32_bf16(a, b, c, 0, 0, 0);
}

// fp32 -> bf16 bits, round-to-nearest-even
__device__ __forceinline__ unsigned short f2b(float f) {
  unsigned int u = __builtin_bit_cast(unsigned int, f);
  return (unsigned short)((u + 0x7fffu + ((u >> 16) & 1u)) >> 16);
}

__device__ __forceinline__ bf16x8 cvt8(float4 a, float4 b) {
  bf16x8 r;
  r[0] = (short)f2b(a.x); r[1] = (short)f2b(a.y); r[2] = (short)f2b(a.z); r[3] = (short)f2b(a.w);
  r[4] = (short)f2b(b.x); r[5] = (short)f2b(b.y); r[6] = (short)f2b(b.z); r[7] = (short)f2b(b.w);
  return r;
}

// async global->LDS, 16 B per lane (m97 pattern; LDS dest = wave-uniform base + lane*16)
__device__ __forceinline__ void gld_lds16(const void* g, void* l) {
  __builtin_amdgcn_global_load_lds((const __attribute__((address_space(1))) unsigned int*)g,
                                   (__attribute__((address_space(3))) unsigned int*)l, 16, 0, 0);
}

// x fp32 -> bf16, 8 elems/thread (16-B loads x2, 16-B store)
__global__ void cast8(const float* __restrict__ in, unsigned short* __restrict__ out) {
  int i = (blockIdx.x * 256 + threadIdx.x) * 8;
  float4 a = *reinterpret_cast<const float4*>(in + i);
  float4 b = *reinterpret_cast<const float4*>(in + i + 4);
  *reinterpret_cast<bf16x8*>(out + i) = cvt8(a, b);
}

// wcT[j][m] = sum_{hd} fc_w[j][hd] * w_v[hd>>6][m][hd&63]   (1024x1024 bf16 out)
// 512 threads: waves (wk, wr, wc); wk splits K=1024 into 2 halves; LDS reduction at end.
__global__ __launch_bounds__(512) void fold_w(const float* __restrict__ fcw,
                                              const float* __restrict__ wv,
                                              unsigned short* __restrict__ wcT) {
  int wid = threadIdx.x >> 6, lane = threadIdx.x & 63, l16 = lane & 15, quad = lane >> 4;
  int wk = wid >> 2, wr = (wid >> 1) & 1, wc = wid & 1;
  int row0 = blockIdx.y * 64 + wr * 32;   // j
  int col0 = blockIdx.x * 64 + wc * 32;   // m
  f32x4 acc[2][2];
#pragma unroll
  for (int a = 0; a < 2; a++)
#pragma unroll
    for (int b = 0; b < 2; b++) acc[a][b] = (f32x4){0.f, 0.f, 0.f, 0.f};

  for (int k0 = wk * 512; k0 < wk * 512 + 512; k0 += 32) {
    int kk = k0 + quad * 8;
    int h = kk >> 6, d = kk & 63;
    bf16x8 af[2], bfr[2];
#pragma unroll
    for (int rt = 0; rt < 2; rt++) {
      const float* pa = fcw + (row0 + rt * 16 + l16) * 1024 + kk;
      af[rt] = cvt8(*reinterpret_cast<const float4*>(pa), *reinterpret_cast<const float4*>(pa + 4));
    }
#pragma unroll
    for (int ct = 0; ct < 2; ct++) {
      const float* pb = wv + h * 65536 + (col0 + ct * 16 + l16) * 64 + d;
      bfr[ct] = cvt8(*reinterpret_cast<const float4*>(pb), *reinterpret_cast<const float4*>(pb + 4));
    }
#pragma unroll
    for (int rt = 0; rt < 2; rt++)
#pragma unroll
      for (int ct = 0; ct < 2; ct++) acc[rt][ct] = mfma16(af[rt], bfr[ct], acc[rt][ct]);
  }

  __shared__ f32x4 red[4][64][4];
  if (wk == 1) {
#pragma unroll
    for (int rt = 0; rt < 2; rt++)
#pragma unroll
      for (int ct = 0; ct < 2; ct++) red[wid & 3][lane][rt * 2 + ct] = acc[rt][ct];
  }
  __syncthreads();
  if (wk == 0) {
#pragma unroll
    for (int rt = 0; rt < 2; rt++)
#pragma unroll
      for (int ct = 0; ct < 2; ct++) {
        f32x4 s = acc[rt][ct];
        f32x4 o = red[wid & 3][lane][rt * 2 + ct];
        int j0 = row0 + rt * 16 + quad * 4;
        int m = col0 + ct * 16 + l16;
#pragma unroll
        for (int r = 0; r < 4; r++) wcT[(j0 + r) * 1024 + m] = f2b(s[r] + o[r]);
      }
  }
}

// out[i][j] = sum_m xb[i][m]*wcT[j][m] + fcb[j].  M=8192,N=1024,K=1024.
// BK=64 as two m97-style 32-k slabs (64-B row stride preserved): per iter
// 8 gld_lds16 + 2 barriers + 16 ds_read_b128 + 32 MFMA. LDS 32 KB.
// grid (M-fastest, 64x8): consecutive blocks share B -> L2-resident, A fetched once per N-tile.
__global__ __launch_bounds__(256) void final_gemm(const unsigned short* __restrict__ xb,
                                                  const unsigned short* __restrict__ wcT,
                                                  const float* __restrict__ fcb,
                                                  float* __restrict__ out) {
  __shared__ __align__(16) unsigned short As[2 * 128 * 32];  // [slab][row][32]
  __shared__ __align__(16) unsigned short Bs[2 * 128 * 32];
  int t = threadIdx.x, wid = t >> 6, lane = t & 63, l16 = lane & 15, quad = lane >> 4;
  int wr = wid >> 1, wc = wid & 1;
  int row0 = blockIdx.x * 128;   // M tile
  int col0 = blockIdx.y * 128;   // N tile

  // staging: wave w issues 4 gld_lds16; block index blk = w*4+j in 0..15.
  // blk covers LDS bytes [blk*1024, blk*1024+1024) = slab blk>>3, rows (blk&7)*16 .. +15.
  // lane covers row r0 + (lane>>2), k-quad lane&3 of that slab (global k offset s*32 + kq*8).
  int w4 = wid * 4;
  const unsigned short* Ap[4];
  const unsigned short* Bp[4];
#pragma unroll
  for (int j = 0; j < 4; j++) {
    int blk = w4 + j;
    int s = blk >> 3, r0 = (blk & 7) * 16;
    int row = r0 + (lane >> 2), kq = lane & 3;
    Ap[j] = xb + (row0 + row) * 1024 + s * 32 + kq * 8;
    Bp[j] = wcT + (col0 + row) * 1024 + s * 32 + kq * 8;
  }

  f32x4 acc[16];
#pragma unroll
  for (int i = 0; i < 16; i++) acc[i] = (f32x4){0.f, 0.f, 0.f, 0.f};

  for (int k0 = 0; k0 < 1024; k0 += 64) {
    __syncthreads();
#pragma unroll
    for (int j = 0; j < 4; j++) {
      int off = (w4 + j) * 512 + lane * 8;
      gld_lds16(Ap[j] + k0, &As[off]);
      gld_lds16(Bp[j] + k0, &Bs[off]);
    }
    __syncthreads();

#pragma unroll
    for (int s = 0; s < 2; s++) {
      bf16x8 af[4], bfr[4];
#pragma unroll
      for (int rt = 0; rt < 4; rt++)
        af[rt] = *reinterpret_cast<const bf16x8*>(&As[s * 4096 + (wr * 64 + rt * 16 + l16) * 32 + quad * 8]);
#pragma unroll
      for (int ct = 0; ct < 4; ct++)
        bfr[ct] = *reinterpret_cast<const bf16x8*>(&Bs[s * 4096 + (wc * 64 + ct * 16 + l16) * 32 + quad * 8]);
#pragma unroll
      for (int rt = 0; rt < 4; rt++)
#pragma unroll
        for (int ct = 0; ct < 4; ct++)
          acc[rt * 4 + ct] = mfma16(af[rt], bfr[ct], acc[rt * 4 + ct]);
    }
  }

#pragma unroll
  for (int ct = 0; ct < 4; ct++) {
    int j = col0 + wc * 64 + ct * 16 + l16;
    float bias = fcb[j];
#pragma unroll
    for (int rt = 0; rt < 4; rt++) {
      int i0 = row0 + wr * 64 + rt * 16 + quad * 4;
      f32x4 a = acc[rt * 4 + ct];
#pragma unroll
      for (int r = 0; r < 4; r++) out[(i0 + r) * 1024 + j] = a[r] + bias;
    }
  }
}

extern "C" void kernel_launch(void* const* d_in, const int* in_sizes, int n_in,
                              void* d_out, int out_size, void* d_ws, size_t ws_size,
                              hipStream_t stream) {
  const float* x   = (const float*)d_in[0];
  // d_in[1] mask, d_in[2] w_q, d_in[3] w_k: dead per reference semantics
  const float* wv  = (const float*)d_in[4];
  const float* fcw = (const float*)d_in[5];
  const float* fcb = (const float*)d_in[6];
  float* out = (float*)d_out;

  char* ws = (char*)d_ws;
  unsigned short* xb  = (unsigned short*)(ws);              // 16 MB (8192x1024 bf16)
  unsigned short* wcT = (unsigned short*)(ws + 16777216);   // 2 MB  (1024x1024 bf16)

  cast8<<<4096, 256, 0, stream>>>(x, xb);
  fold_w<<<dim3(16, 16), 512, 0, stream>>>(fcw, wv, wcT);
  final_gemm<<<dim3(64, 8), 256, 0, stream>>>(xb, wcT, fcb, out);
}